// Round 12
// baseline (1425.961 us; speedup 1.0000x reference)
//
#include <hip/hip_runtime.h>

// R12 = ABLATION ROUND. Real computation = R7 verbatim (42.2us best).
// Five probe dispatches (template<MODE,REPS>) decompose the 42us wall:
//   MODE 0: full body (R7-identical)        REPS=4
//   MODE 1: stage-only (no compute)         REPS=6
//   MODE 2: compute-only (no loop staging)  REPS=12
//   MODE 3: full, no per-step barrier       REPS=6
//   MODE 4: MFMA+pool only (reg fragments)  REPS=32
// Probes write to dummy ws regions; internal repeats push each above the
// 75us harness fills so all five surface in rocprof top-5.

using short8 = __attribute__((ext_vector_type(8))) short;
using f32x4  = __attribute__((ext_vector_type(4))) float;

__device__ __forceinline__ unsigned short f2bf_rn(float f) {
  unsigned u = __float_as_uint(f);
  return (unsigned short)((u + 0x7FFFu + ((u >> 16) & 1u)) >> 16);
}

__global__ __launch_bounds__(256) void prep_w(const float* __restrict__ cw,
                                              short* __restrict__ Bp) {
  int i = threadIdx.x + blockIdx.x * 256;
  if (i >= 576) return;
  int g = i >> 6, l = i & 63;
  int co = l & 15, kw = l >> 4;
  int kd = g / 3, kh = g % 3;
  short8 o;
#pragma unroll
  for (int j = 0; j < 8; ++j) {
    float v = (kw < 3) ? cw[(co * 8 + j) * 27 + kd * 9 + kh * 3 + kw] : 0.0f;
    o[j] = (short)f2bf_rn(v);
  }
  *(short8*)(Bp + (size_t)i * 8) = o;
}

template <int MODE, int REPS>
__global__ __launch_bounds__(256, 4) void conv_k(const float* __restrict__ x,
                                                 const short* __restrict__ Bp,
                                                 float* __restrict__ partial) {
  __shared__ __align__(16) char lds[6 * 3072];
  __shared__ float red[4];

  const int bid = blockIdx.x;                    // 1024 blocks
  const int swz = (bid & 7) * 128 + (bid >> 3);
  const int b = swz >> 3, q = swz & 7;
  const int t = threadIdx.x, lane = t & 63, wv = t >> 6;
  const int nrows = (q == 7) ? 4 : 6;
  const int row0 = 4 * q;
  const int sites = nrows * 16;
  const float* xb = x + (size_t)b * 262144;

  const bool sact = t < 2 * sites;
  const int spl = (t >= sites) ? 1 : 0;
  const int ss = sact ? (t - spl * sites) : 0;
  const int sr = ss >> 4, swg = ss & 15;
  const float* gsite = xb + (row0 + sr) * 32 + swg * 2;

  auto issueB = [&](int pb, float2* v) {
    if (!sact) return;
    const float* gp = gsite + (pb + spl) * 1024;
#pragma unroll
    for (int ci = 0; ci < 8; ++ci) v[ci] = *(const float2*)(gp + ci * 32768);
  };
  auto writeB = [&](int pb, const float2* v) {
    if (!sact) return;
    char* sb = lds + ((pb + spl) % 6) * 3072 + sr * 512;
#pragma unroll
    for (int wi = 0; wi < 2; ++wi) {
      const int w = swg * 2 + wi;
      uint4 o;
      o.x = __builtin_amdgcn_perm(__float_as_uint(((const float*)&v[1])[wi]),
                                  __float_as_uint(((const float*)&v[0])[wi]), 0x07060302u);
      o.y = __builtin_amdgcn_perm(__float_as_uint(((const float*)&v[3])[wi]),
                                  __float_as_uint(((const float*)&v[2])[wi]), 0x07060302u);
      o.z = __builtin_amdgcn_perm(__float_as_uint(((const float*)&v[5])[wi]),
                                  __float_as_uint(((const float*)&v[4])[wi]), 0x07060302u);
      o.w = __builtin_amdgcn_perm(__float_as_uint(((const float*)&v[7])[wi]),
                                  __float_as_uint(((const float*)&v[6])[wi]), 0x07060302u);
      *(uint4*)(sb + ((w * 16) ^ (((w >> 3) & 3) << 4))) = o;
    }
  };

  short8 Bw[9];
#pragma unroll
  for (int g = 0; g < 9; ++g)
    Bw[g] = *(const short8*)(Bp + ((size_t)g * 64 + lane) * 8);

  const int m = lane & 15, tg = lane >> 4;
  const int w0 = m + tg;
  int w1 = m + 16 + tg; if (w1 > 31) w1 = 31;
  const int wb0 = (w0 * 16) ^ (((w0 >> 3) & 3) << 4);
  const int wb1 = (w1 * 16) ^ (((w1 >> 3) & 3) << 4);

  const bool docomp = (q < 7) || (wv < 2);
  const int op = (q < 7) ? (wv >> 1) : 0;
  const int c  = (q < 7) ? (wv & 1) : wv;
  const int wbase = (c ? wb1 : wb0) + (2 * op) * 512;

  float sum = 0.0f;

  auto pool = [&](f32x4 (&cc)[2][2]) {
#pragma unroll
    for (int p2 = 0; p2 < 2; ++p2) {
      float v = fmaxf(fmaxf(fmaxf(cc[0][0][2 * p2], cc[0][0][2 * p2 + 1]),
                            fmaxf(cc[0][1][2 * p2], cc[0][1][2 * p2 + 1])),
                      fmaxf(fmaxf(cc[1][0][2 * p2], cc[1][0][2 * p2 + 1]),
                            fmaxf(cc[1][1][2 * p2], cc[1][1][2 * p2 + 1])));
      const bool inval = (c == 1) && (tg == 3) && (p2 == 1);
      sum += inval ? 0.0f : v;
    }
  };
  // R7-faithful compute: reads interleaved inside the p/rr loop
  auto compute_r7 = [&](int rs0) {
    int sl1 = rs0 + 1;
    int sl2 = rs0 + 2; if (sl2 >= 6) sl2 -= 6;
    int sl3 = rs0 + 3; if (sl3 >= 6) sl3 -= 6;
    const char* sbp[4] = {lds + rs0 * 3072 + wbase, lds + sl1 * 3072 + wbase,
                          lds + sl2 * 3072 + wbase, lds + sl3 * 3072 + wbase};
    f32x4 cc[2][2] = {};
#pragma unroll
    for (int p = 0; p < 4; ++p) {
#pragma unroll
      for (int rr = 0; rr < 4; ++rr) {
        const short8 a = *(const short8*)(sbp[p] + rr * 512);
        if (p < 3 && rr < 3)
          cc[0][0] = __builtin_amdgcn_mfma_f32_16x16x32_bf16(a, Bw[p * 3 + rr], cc[0][0], 0, 0, 0);
        if (p < 3 && rr > 0)
          cc[0][1] = __builtin_amdgcn_mfma_f32_16x16x32_bf16(a, Bw[p * 3 + rr - 1], cc[0][1], 0, 0, 0);
        if (p > 0 && rr < 3)
          cc[1][0] = __builtin_amdgcn_mfma_f32_16x16x32_bf16(a, Bw[(p - 1) * 3 + rr], cc[1][0], 0, 0, 0);
        if (p > 0 && rr > 0)
          cc[1][1] = __builtin_amdgcn_mfma_f32_16x16x32_bf16(a, Bw[(p - 1) * 3 + rr - 1], cc[1][1], 0, 0, 0);
      }
    }
    pool(cc);
  };
  auto mfma_reg = [&](const short8 (&f)[4], int p, f32x4 (&cc)[2][2]) {
#pragma unroll
    for (int rr = 0; rr < 4; ++rr) {
      const short8 a = f[rr];
      if (p < 3 && rr < 3)
        cc[0][0] = __builtin_amdgcn_mfma_f32_16x16x32_bf16(a, Bw[p * 3 + rr], cc[0][0], 0, 0, 0);
      if (p < 3 && rr > 0)
        cc[0][1] = __builtin_amdgcn_mfma_f32_16x16x32_bf16(a, Bw[p * 3 + rr - 1], cc[0][1], 0, 0, 0);
      if (p > 0 && rr < 3)
        cc[1][0] = __builtin_amdgcn_mfma_f32_16x16x32_bf16(a, Bw[(p - 1) * 3 + rr], cc[1][0], 0, 0, 0);
      if (p > 0 && rr > 0)
        cc[1][1] = __builtin_amdgcn_mfma_f32_16x16x32_bf16(a, Bw[(p - 1) * 3 + rr - 1], cc[1][1], 0, 0, 0);
    }
  };

  short8 g0[4], g1[4];  // MODE 4 register fragments (2 planes, reused)

#pragma unroll 1
  for (int rep = 0; rep < REPS; ++rep) {
    // prologue: stage planes 0..3 (MODE 2: 0..5 so all ring slots are valid)
    {
      float2 va[8], vb[8];
      issueB(0, va); issueB(2, vb);
      writeB(0, va); writeB(2, vb);
      if constexpr (MODE == 2) {
        float2 vc[8];
        issueB(4, vc); writeB(4, vc);
      }
    }
    __syncthreads();

    if constexpr (MODE == 4) {
      if (docomp) {
#pragma unroll
        for (int rr = 0; rr < 4; ++rr) {
          g0[rr] = *(const short8*)(lds + 0 * 3072 + wbase + rr * 512);
          g1[rr] = *(const short8*)(lds + 1 * 3072 + wbase + rr * 512);
        }
      }
    }

    int rs0 = 0;
#pragma unroll 1
    for (int st = 0; st < 15; ++st) {
      const bool more = st < 14;
      float2 va[8];
      if constexpr (MODE == 0 || MODE == 1 || MODE == 3) {
        if (more) issueB(2 * st + 4, va);
      }
      if constexpr (MODE == 0 || MODE == 2 || MODE == 3) {
        if (docomp) compute_r7(rs0);
      }
      if constexpr (MODE == 4) {
        if (docomp) {
          f32x4 cc[2][2] = {};
          mfma_reg(g0, 0, cc); mfma_reg(g1, 1, cc);
          mfma_reg(g0, 2, cc); mfma_reg(g1, 3, cc);
          pool(cc);
        }
      }
      if constexpr (MODE == 0 || MODE == 1 || MODE == 3) {
        if (more) writeB(2 * st + 4, va);
      }
      if constexpr (MODE == 0 || MODE == 1 || MODE == 2) __syncthreads();
      rs0 += 2; if (rs0 >= 6) rs0 -= 6;
    }

    if constexpr (MODE == 1) {
      // keep staging live: read back one LDS float per thread
      sum += ((const float*)lds)[(t << 4) | 1];
    }
    __syncthreads();  // rep boundary (ring restage safety)
  }

#pragma unroll
  for (int off = 32; off; off >>= 1) sum += __shfl_down(sum, off);
  if (lane == 0) red[wv] = sum;
  __syncthreads();
  if (t == 0) partial[b * 8 + q] = red[0] + red[1] + red[2] + red[3];
}

__global__ __launch_bounds__(128) void finalize(const float* __restrict__ partial,
                                                const float* __restrict__ cb,
                                                const float* __restrict__ bias,
                                                float* __restrict__ out) {
  const int b = threadIdx.x;
  float k = 0.0f;
#pragma unroll
  for (int c = 0; c < 16; ++c) k += cb[c] * 0.5f + bias[c];
  float s = 0.0f;
#pragma unroll
  for (int q = 0; q < 8; ++q) s += partial[b * 8 + q];
  out[b] = s * (1.0f / 6750.0f) + k;
}

extern "C" void kernel_launch(void* const* d_in, const int* in_sizes, int n_in,
                              void* d_out, int out_size, void* d_ws, size_t ws_size,
                              hipStream_t stream) {
  const float* x    = (const float*)d_in[0];
  const float* cw   = (const float*)d_in[1];
  const float* cb   = (const float*)d_in[2];
  const float* bias = (const float*)d_in[3];
  float* out = (float*)d_out;

  short* Bp      = (short*)d_ws;                    // 9216 B
  float* partial = (float*)((char*)d_ws + 32768);   // real partials (1024 f)
  float* dumS    = (float*)((char*)d_ws + 65536);
  float* dumC    = (float*)((char*)d_ws + 65536 + 8192);
  float* dumN    = (float*)((char*)d_ws + 65536 + 16384);
  float* dumM    = (float*)((char*)d_ws + 65536 + 24576);
  float* dumF    = (float*)((char*)d_ws + 65536 + 32768);

  prep_w<<<3, 256, 0, stream>>>(cw, Bp);
  // ---- probes (dummy outputs; internal repeats to surface in top-5) ----
  conv_k<1, 6><<<1024, 256, 0, stream>>>(x, Bp, dumS);    // stage-only
  conv_k<2, 12><<<1024, 256, 0, stream>>>(x, Bp, dumC);   // compute-only
  conv_k<3, 6><<<1024, 256, 0, stream>>>(x, Bp, dumN);    // full, no barrier
  conv_k<4, 32><<<1024, 256, 0, stream>>>(x, Bp, dumM);   // mfma-only
  conv_k<0, 4><<<1024, 256, 0, stream>>>(x, Bp, dumF);    // full
  // ---- real computation (R7 schedule = conv_k<0,1>) ----
  conv_k<0, 1><<<1024, 256, 0, stream>>>(x, Bp, partial);
  finalize<<<1, 128, 0, stream>>>(partial, cb, bias, out);
}

// Round 13
// 52.160 us; speedup vs baseline: 27.3381x; 27.3381x over previous
//
#include <hip/hip_runtime.h>

// x: [128,8,32,32,32] f32  cw: [16,8,3,3,3] f32  cb: [16]  bias: [16]  out: [128]
// out[b] = (1/6750)*sum_{c,cells} maxpool2(conv_raw) + sum_c(cb[c]/2 + bias[c])
//
// R13 = R7 compute body (verified) on a 10-slab ring with 2 pd per barrier
// interval: barriers 15->8, write-slots disjoint from ALL interval read-slots,
// op=1 waves process tasks in reverse pd order (de-phase the read burst).

using short8 = __attribute__((ext_vector_type(8))) short;
using f32x4  = __attribute__((ext_vector_type(4))) float;

__device__ __forceinline__ unsigned short f2bf_rn(float f) {
  unsigned u = __float_as_uint(f);
  return (unsigned short)((u + 0x7FFFu + ((u >> 16) & 1u)) >> 16);
}

// Bp[g=kd*3+kh][lane]: 8 bf16 = w[co=lane&15][ci=j][kd][kh][kw=lane>>4]; kw==3 -> 0
__global__ __launch_bounds__(256) void prep_w(const float* __restrict__ cw,
                                              short* __restrict__ Bp) {
  int i = threadIdx.x + blockIdx.x * 256;
  if (i >= 576) return;
  int g = i >> 6, l = i & 63;
  int co = l & 15, kw = l >> 4;
  int kd = g / 3, kh = g % 3;
  short8 o;
#pragma unroll
  for (int j = 0; j < 8; ++j) {
    float v = (kw < 3) ? cw[(co * 8 + j) * 27 + kd * 9 + kh * 3 + kw] : 0.0f;
    o[j] = (short)f2bf_rn(v);
  }
  *(short8*)(Bp + (size_t)i * 8) = o;
}

__global__ __launch_bounds__(256, 4) void conv_mfma(const float* __restrict__ x,
                                                    const short* __restrict__ Bp,
                                                    float* __restrict__ partial) {
  __shared__ __align__(16) char lds[10 * 3072];  // 10-slab ring (30720 B)
  __shared__ float red[4];

  const int bid = blockIdx.x;                    // 1024 blocks = 4/CU
  const int swz = (bid & 7) * 128 + (bid >> 3);  // XCD-chunk, bijective
  const int b = swz >> 3, q = swz & 7;           // q: oh rows 4q..4q+3 (q=7: 2 rows)
  const int t = threadIdx.x, lane = t & 63, wv = t >> 6;
  const int nrows = (q == 7) ? 4 : 6;
  const int row0 = 4 * q;
  const int sites = nrows * 16;
  const float* xb = x + (size_t)b * 262144;

  // ---- staging decode (R7-identical) ----
  const bool sact = t < 2 * sites;
  const int spl = (t >= sites) ? 1 : 0;
  const int ss = sact ? (t - spl * sites) : 0;
  const int sr = ss >> 4, swg = ss & 15;
  const float* gsite = xb + (row0 + sr) * 32 + swg * 2;  // + plane*1024 + ci*32768

  auto issueB = [&](int pb, float2* v) {  // pb = plane base (even)
    if (!sact) return;
    const float* gp = gsite + (pb + spl) * 1024;
#pragma unroll
    for (int ci = 0; ci < 8; ++ci) v[ci] = *(const float2*)(gp + ci * 32768);
  };
  auto writeS = [&](int sl0, const float2* v) {  // slots sl0+spl (mod 10)
    if (!sact) return;
    int slot = sl0 + spl; if (slot >= 10) slot -= 10;
    char* sb = lds + slot * 3072 + sr * 512;
#pragma unroll
    for (int wi = 0; wi < 2; ++wi) {
      const int w = swg * 2 + wi;
      uint4 o;  // truncation bf16 pack [ci0..ci7] (verified R6/R7)
      o.x = __builtin_amdgcn_perm(__float_as_uint(((const float*)&v[1])[wi]),
                                  __float_as_uint(((const float*)&v[0])[wi]), 0x07060302u);
      o.y = __builtin_amdgcn_perm(__float_as_uint(((const float*)&v[3])[wi]),
                                  __float_as_uint(((const float*)&v[2])[wi]), 0x07060302u);
      o.z = __builtin_amdgcn_perm(__float_as_uint(((const float*)&v[5])[wi]),
                                  __float_as_uint(((const float*)&v[4])[wi]), 0x07060302u);
      o.w = __builtin_amdgcn_perm(__float_as_uint(((const float*)&v[7])[wi]),
                                  __float_as_uint(((const float*)&v[6])[wi]), 0x07060302u);
      *(uint4*)(sb + ((w * 16) ^ (((w >> 3) & 3) << 4))) = o;
    }
  };

  // ---- B fragments (9 (kd,kh) groups, block-invariant) ----
  short8 Bw[9];
#pragma unroll
  for (int g = 0; g < 9; ++g)
    Bw[g] = *(const short8*)(Bp + ((size_t)g * 64 + lane) * 8);

  // ---- per-lane A addressing (verified R3/R7) ----
  const int m = lane & 15, tg = lane >> 4;
  const int w0 = m + tg;
  int w1 = m + 16 + tg; if (w1 > 31) w1 = 31;  // clamp hits only masked/pad lanes
  const int wb0 = (w0 * 16) ^ (((w0 >> 3) & 3) << 4);
  const int wb1 = (w1 * 16) ^ (((w1 >> 3) & 3) << 4);

  // ---- task mapping ----
  // q<7: wave = (op = wv>>1, c = wv&1); two tasks/interval (pd 2k+rot first,
  //      rot = op -> read burst split across plane-sets).
  // q=7: wave = (dp = wv>>1, c = wv&1); one task/interval at pd 2k+dp, op=0.
  const int op = wv >> 1, c = wv & 1;
  const int rowoff = (q < 7) ? (2 * op) : 0;
  const int wbase = (c ? wb1 : wb0) + rowoff * 512;
  const int rot = (q < 7) ? op : 0;   // q<7 task order
  const int dp7 = op;                 // q=7 pd selector

  float sum = 0.0f;
  auto compute = [&](int rs) {  // rs = slot of plane 2*pd (mod 10)
    int s0 = rs;      if (s0 >= 10) s0 -= 10;
    int s1 = rs + 1;  if (s1 >= 10) s1 -= 10;
    int s2 = rs + 2;  if (s2 >= 10) s2 -= 10;
    int s3 = rs + 3;  if (s3 >= 10) s3 -= 10;
    const char* sbp[4] = {lds + s0 * 3072 + wbase, lds + s1 * 3072 + wbase,
                          lds + s2 * 3072 + wbase, lds + s3 * 3072 + wbase};
    f32x4 cc[2][2] = {};
#pragma unroll
    for (int p = 0; p < 4; ++p) {
#pragma unroll
      for (int rr = 0; rr < 4; ++rr) {
        const short8 a = *(const short8*)(sbp[p] + rr * 512);
        if (p < 3 && rr < 3)
          cc[0][0] = __builtin_amdgcn_mfma_f32_16x16x32_bf16(a, Bw[p * 3 + rr], cc[0][0], 0, 0, 0);
        if (p < 3 && rr > 0)
          cc[0][1] = __builtin_amdgcn_mfma_f32_16x16x32_bf16(a, Bw[p * 3 + rr - 1], cc[0][1], 0, 0, 0);
        if (p > 0 && rr < 3)
          cc[1][0] = __builtin_amdgcn_mfma_f32_16x16x32_bf16(a, Bw[(p - 1) * 3 + rr], cc[1][0], 0, 0, 0);
        if (p > 0 && rr > 0)
          cc[1][1] = __builtin_amdgcn_mfma_f32_16x16x32_bf16(a, Bw[(p - 1) * 3 + rr - 1], cc[1][1], 0, 0, 0);
      }
    }
#pragma unroll
    for (int p2 = 0; p2 < 2; ++p2) {
      float v = fmaxf(fmaxf(fmaxf(cc[0][0][2 * p2], cc[0][0][2 * p2 + 1]),
                            fmaxf(cc[0][1][2 * p2], cc[0][1][2 * p2 + 1])),
                      fmaxf(fmaxf(cc[1][0][2 * p2], cc[1][0][2 * p2 + 1]),
                            fmaxf(cc[1][1][2 * p2], cc[1][1][2 * p2 + 1])));
      const bool inval = (c == 1) && (tg == 3) && (p2 == 1);  // pw 15 invalid
      sum += inval ? 0.0f : v;
    }
  };

  // ---- prologue: stage planes 0..5 into slots 0..5 ----
  {
    float2 va[8], vb[8];
    issueB(0, va);
    issueB(2, vb);
    writeS(0, va);
    issueB(4, va);
    writeS(2, vb);
    writeS(4, va);
  }
  __syncthreads();

  // ---- 7 intervals, each = 2 pd (0..13); writes hit slots r0+6..r0+9,
  //      reads hit r0..r0+5 -> disjoint mod 10 regardless of wave skew ----
  int r0 = 0;
#pragma unroll 1
  for (int k = 0; k < 7; ++k) {
    const bool haveB = (k < 6);
    float2 va[8], vb[8];
    issueB(4 * k + 6, va);                 // planes for next interval (A)

    if (q < 7) compute(r0 + 2 * rot);      // first task
    else       compute(r0 + 2 * dp7);      // q=7: its single task

    writeS(r0 + 6, va);                    // vmcnt covered by compute above
    if (haveB) issueB(4 * k + 8, vb);      // planes for next interval (B)

    if (q < 7) compute(r0 + 2 * (1 - rot));  // second task

    if (haveB) writeS(r0 + 8, vb);         // covered by second compute

    __syncthreads();
    r0 += 4; if (r0 >= 10) r0 -= 10;
  }

  // ---- tail: pd = 14 (planes 28..31 at slots r0..r0+3) ----
  if (q < 7) compute(r0);
  else if (dp7 == 0) compute(r0);

  // ---- block reduction ----
#pragma unroll
  for (int off = 32; off; off >>= 1) sum += __shfl_down(sum, off);
  if (lane == 0) red[wv] = sum;
  __syncthreads();
  if (t == 0) partial[b * 8 + q] = red[0] + red[1] + red[2] + red[3];
}

__global__ __launch_bounds__(128) void finalize(const float* __restrict__ partial,
                                                const float* __restrict__ cb,
                                                const float* __restrict__ bias,
                                                float* __restrict__ out) {
  const int b = threadIdx.x;  // 128 threads, 1 block
  float k = 0.0f;
#pragma unroll
  for (int c = 0; c < 16; ++c) k += cb[c] * 0.5f + bias[c];
  float s = 0.0f;
#pragma unroll
  for (int q = 0; q < 8; ++q) s += partial[b * 8 + q];
  out[b] = s * (1.0f / 6750.0f) + k;
}

extern "C" void kernel_launch(void* const* d_in, const int* in_sizes, int n_in,
                              void* d_out, int out_size, void* d_ws, size_t ws_size,
                              hipStream_t stream) {
  const float* x    = (const float*)d_in[0];
  const float* cw   = (const float*)d_in[1];
  const float* cb   = (const float*)d_in[2];
  const float* bias = (const float*)d_in[3];
  float* out = (float*)d_out;

  short* Bp      = (short*)d_ws;                   // 576*16 B = 9216 B
  float* partial = (float*)((char*)d_ws + 32768);  // 1024 floats

  prep_w<<<3, 256, 0, stream>>>(cw, Bp);
  conv_mfma<<<1024, 256, 0, stream>>>(x, Bp, partial);
  finalize<<<1, 128, 0, stream>>>(partial, cb, bias, out);
}

// Round 14
// 46.070 us; speedup vs baseline: 30.9519x; 1.1322x over previous
//
#include <hip/hip_runtime.h>

// x: [128,8,32,32,32] f32  cw: [16,8,3,3,3] f32  cb: [16]  bias: [16]  out: [128]
// out[b] = (1/6750)*sum_{c,cells} maxpool2(conv_raw) + sum_c(cb[c]/2 + bias[c])
//
// R14 = R13 (10-slab ring, 2 pd per barrier interval, 8 barriers) with:
//  (1) __launch_bounds__(256,2): lift the 64-VGPR cap that spilled R8-R13
//      (schedule needs ~110; <=128 still gives 4 blocks/CU, LDS 30.7KB*4<160)
//  (2) interval loop fully unrolled -> all ring-slot addresses compile-time.

using short8 = __attribute__((ext_vector_type(8))) short;
using f32x4  = __attribute__((ext_vector_type(4))) float;

__device__ __forceinline__ unsigned short f2bf_rn(float f) {
  unsigned u = __float_as_uint(f);
  return (unsigned short)((u + 0x7FFFu + ((u >> 16) & 1u)) >> 16);
}

// Bp[g=kd*3+kh][lane]: 8 bf16 = w[co=lane&15][ci=j][kd][kh][kw=lane>>4]; kw==3 -> 0
__global__ __launch_bounds__(256) void prep_w(const float* __restrict__ cw,
                                              short* __restrict__ Bp) {
  int i = threadIdx.x + blockIdx.x * 256;
  if (i >= 576) return;
  int g = i >> 6, l = i & 63;
  int co = l & 15, kw = l >> 4;
  int kd = g / 3, kh = g % 3;
  short8 o;
#pragma unroll
  for (int j = 0; j < 8; ++j) {
    float v = (kw < 3) ? cw[(co * 8 + j) * 27 + kd * 9 + kh * 3 + kw] : 0.0f;
    o[j] = (short)f2bf_rn(v);
  }
  *(short8*)(Bp + (size_t)i * 8) = o;
}

__global__ __launch_bounds__(256, 2) void conv_mfma(const float* __restrict__ x,
                                                    const short* __restrict__ Bp,
                                                    float* __restrict__ partial) {
  __shared__ __align__(16) char lds[10 * 3072];  // 10-slab ring (30720 B)
  __shared__ float red[4];

  const int bid = blockIdx.x;                    // 1024 blocks = 4/CU
  const int swz = (bid & 7) * 128 + (bid >> 3);  // XCD-chunk, bijective
  const int b = swz >> 3, q = swz & 7;           // q: oh rows 4q..4q+3 (q=7: 2 rows)
  const int t = threadIdx.x, lane = t & 63, wv = t >> 6;
  const int nrows = (q == 7) ? 4 : 6;
  const int row0 = 4 * q;
  const int sites = nrows * 16;
  const float* xb = x + (size_t)b * 262144;

  // ---- staging decode (R7-identical) ----
  const bool sact = t < 2 * sites;
  const int spl = (t >= sites) ? 1 : 0;
  const int ss = sact ? (t - spl * sites) : 0;
  const int sr = ss >> 4, swg = ss & 15;
  const float* gsite = xb + (row0 + sr) * 32 + swg * 2;  // + plane*1024 + ci*32768

  auto issueB = [&](int pb, float2* v) {  // pb = plane base (even)
    if (!sact) return;
    const float* gp = gsite + (pb + spl) * 1024;
#pragma unroll
    for (int ci = 0; ci < 8; ++ci) v[ci] = *(const float2*)(gp + ci * 32768);
  };
  auto writeS = [&](int sl0, const float2* v) {  // slots sl0+spl (sl0 compile-time)
    if (!sact) return;
    int slot = sl0 + spl; if (slot >= 10) slot -= 10;
    char* sb = lds + slot * 3072 + sr * 512;
#pragma unroll
    for (int wi = 0; wi < 2; ++wi) {
      const int w = swg * 2 + wi;
      uint4 o;  // truncation bf16 pack [ci0..ci7] (verified R6/R7)
      o.x = __builtin_amdgcn_perm(__float_as_uint(((const float*)&v[1])[wi]),
                                  __float_as_uint(((const float*)&v[0])[wi]), 0x07060302u);
      o.y = __builtin_amdgcn_perm(__float_as_uint(((const float*)&v[3])[wi]),
                                  __float_as_uint(((const float*)&v[2])[wi]), 0x07060302u);
      o.z = __builtin_amdgcn_perm(__float_as_uint(((const float*)&v[5])[wi]),
                                  __float_as_uint(((const float*)&v[4])[wi]), 0x07060302u);
      o.w = __builtin_amdgcn_perm(__float_as_uint(((const float*)&v[7])[wi]),
                                  __float_as_uint(((const float*)&v[6])[wi]), 0x07060302u);
      *(uint4*)(sb + ((w * 16) ^ (((w >> 3) & 3) << 4))) = o;
    }
  };

  // ---- B fragments (9 (kd,kh) groups, block-invariant) ----
  short8 Bw[9];
#pragma unroll
  for (int g = 0; g < 9; ++g)
    Bw[g] = *(const short8*)(Bp + ((size_t)g * 64 + lane) * 8);

  // ---- per-lane A addressing (verified R3/R7) ----
  const int m = lane & 15, tg = lane >> 4;
  const int w0 = m + tg;
  int w1 = m + 16 + tg; if (w1 > 31) w1 = 31;  // clamp hits only masked/pad lanes
  const int wb0 = (w0 * 16) ^ (((w0 >> 3) & 3) << 4);
  const int wb1 = (w1 * 16) ^ (((w1 >> 3) & 3) << 4);

  // ---- task mapping (R13-identical) ----
  const int op = wv >> 1, c = wv & 1;
  const int rowoff = (q < 7) ? (2 * op) : 0;
  const int wbase = (c ? wb1 : wb0) + rowoff * 512;
  const int rot = (q < 7) ? op : 0;   // q<7 task order
  const int dp7 = op;                 // q=7 pd selector

  float sum = 0.0f;
  auto compute = [&](int rs) {  // rs = slot of plane 2*pd; compile-time after unroll
    int s0 = rs;      if (s0 >= 10) s0 -= 10;
    int s1 = rs + 1;  if (s1 >= 10) s1 -= 10;
    int s2 = rs + 2;  if (s2 >= 10) s2 -= 10;
    int s3 = rs + 3;  if (s3 >= 10) s3 -= 10;
    const char* sbp[4] = {lds + s0 * 3072 + wbase, lds + s1 * 3072 + wbase,
                          lds + s2 * 3072 + wbase, lds + s3 * 3072 + wbase};
    f32x4 cc[2][2] = {};
#pragma unroll
    for (int p = 0; p < 4; ++p) {
#pragma unroll
      for (int rr = 0; rr < 4; ++rr) {
        const short8 a = *(const short8*)(sbp[p] + rr * 512);
        if (p < 3 && rr < 3)
          cc[0][0] = __builtin_amdgcn_mfma_f32_16x16x32_bf16(a, Bw[p * 3 + rr], cc[0][0], 0, 0, 0);
        if (p < 3 && rr > 0)
          cc[0][1] = __builtin_amdgcn_mfma_f32_16x16x32_bf16(a, Bw[p * 3 + rr - 1], cc[0][1], 0, 0, 0);
        if (p > 0 && rr < 3)
          cc[1][0] = __builtin_amdgcn_mfma_f32_16x16x32_bf16(a, Bw[(p - 1) * 3 + rr], cc[1][0], 0, 0, 0);
        if (p > 0 && rr > 0)
          cc[1][1] = __builtin_amdgcn_mfma_f32_16x16x32_bf16(a, Bw[(p - 1) * 3 + rr - 1], cc[1][1], 0, 0, 0);
      }
    }
#pragma unroll
    for (int p2 = 0; p2 < 2; ++p2) {
      float v = fmaxf(fmaxf(fmaxf(cc[0][0][2 * p2], cc[0][0][2 * p2 + 1]),
                            fmaxf(cc[0][1][2 * p2], cc[0][1][2 * p2 + 1])),
                      fmaxf(fmaxf(cc[1][0][2 * p2], cc[1][0][2 * p2 + 1]),
                            fmaxf(cc[1][1][2 * p2], cc[1][1][2 * p2 + 1])));
      const bool inval = (c == 1) && (tg == 3) && (p2 == 1);  // pw 15 invalid
      sum += inval ? 0.0f : v;
    }
  };

  // ---- prologue: stage planes 0..5 into slots 0..5 ----
  {
    float2 va[8], vb[8];
    issueB(0, va);
    issueB(2, vb);
    writeS(0, va);
    issueB(4, va);
    writeS(2, vb);
    writeS(4, va);
  }
  __syncthreads();

  // ---- 7 intervals (FULL unroll -> compile-time slots), each = 2 pd;
  //      reads slots r0..r0+5, writes r0+6..r0+9 -> disjoint mod 10 ----
#pragma unroll
  for (int k = 0; k < 7; ++k) {
    const int r0 = (4 * k) % 10;  // 0,4,8,2,6,0,4 — constant after unroll
    const bool haveB = (k < 6);
    float2 va[8], vb[8];
    issueB(4 * k + 6, va);                 // planes for next interval (A)

    if (q < 7) compute((r0 + 2 * rot) % 10);      // first task
    else       compute((r0 + 2 * dp7) % 10);      // q=7: its single task

    writeS((r0 + 6) % 10, va);             // vmcnt covered by compute above
    if (haveB) issueB(4 * k + 8, vb);      // planes for next interval (B)

    if (q < 7) compute((r0 + 2 * (1 - rot)) % 10);  // second task

    if (haveB) writeS((r0 + 8) % 10, vb);  // covered by second compute

    __syncthreads();
  }

  // ---- tail: pd = 14 (planes 28..31 at slots 8,9,0,1) ----
  if (q < 7) compute(8);
  else if (dp7 == 0) compute(8);

  // ---- block reduction ----
#pragma unroll
  for (int off = 32; off; off >>= 1) sum += __shfl_down(sum, off);
  if (lane == 0) red[wv] = sum;
  __syncthreads();
  if (t == 0) partial[b * 8 + q] = red[0] + red[1] + red[2] + red[3];
}

__global__ __launch_bounds__(128) void finalize(const float* __restrict__ partial,
                                                const float* __restrict__ cb,
                                                const float* __restrict__ bias,
                                                float* __restrict__ out) {
  const int b = threadIdx.x;  // 128 threads, 1 block
  float k = 0.0f;
#pragma unroll
  for (int c = 0; c < 16; ++c) k += cb[c] * 0.5f + bias[c];
  float s = 0.0f;
#pragma unroll
  for (int q = 0; q < 8; ++q) s += partial[b * 8 + q];
  out[b] = s * (1.0f / 6750.0f) + k;
}

extern "C" void kernel_launch(void* const* d_in, const int* in_sizes, int n_in,
                              void* d_out, int out_size, void* d_ws, size_t ws_size,
                              hipStream_t stream) {
  const float* x    = (const float*)d_in[0];
  const float* cw   = (const float*)d_in[1];
  const float* cb   = (const float*)d_in[2];
  const float* bias = (const float*)d_in[3];
  float* out = (float*)d_out;

  short* Bp      = (short*)d_ws;                   // 576*16 B = 9216 B
  float* partial = (float*)((char*)d_ws + 32768);  // 1024 floats

  prep_w<<<3, 256, 0, stream>>>(cw, Bp);
  conv_mfma<<<1024, 256, 0, stream>>>(x, Bp, partial);
  finalize<<<1, 128, 0, stream>>>(partial, cb, bias, out);
}

// Round 15
// 42.416 us; speedup vs baseline: 33.6182x; 1.0861x over previous
//
#include <hip/hip_runtime.h>

// x: [128,8,32,32,32] f32  cw: [16,8,3,3,3] f32  cb: [16]  bias: [16]  out: [128]
// out[b] = (1/6750)*sum_{c,cells} maxpool2(conv_raw) + sum_c(cb[c]/2 + bias[c])
//
// FINAL = R7 (best measured: 42.2us, absmax 0.125). 16x16x32 MFMA implicit-GEMM
// body ((kd,kh)-bundled K, tg=kw, 16 ds_read_b128 : 36 mfma, in-lane 2x2x2
// pooling, XOR swizzle ^((w>>3)&3)<<4) on a 6-slab LDS ring walking pd.
// Block=(b, h-eighth q), 256 thr, 18.4 KB LDS, 4 blocks/CU; issue-before-
// compute staging (1-deep; deeper pipelines spill past the compiler's 64-VGPR
// heuristic — R8-R14 all regressed). Practical HIP-source floor:
// MFMA 17.5us + LDS 19us + staging ~8us, serialized by barrier phase-locking.

using short8 = __attribute__((ext_vector_type(8))) short;
using f32x4  = __attribute__((ext_vector_type(4))) float;

__device__ __forceinline__ unsigned short f2bf_rn(float f) {
  unsigned u = __float_as_uint(f);
  return (unsigned short)((u + 0x7FFFu + ((u >> 16) & 1u)) >> 16);
}

// Bp[g=kd*3+kh][lane]: 8 bf16 = w[co=lane&15][ci=j][kd][kh][kw=lane>>4]; kw==3 -> 0
__global__ __launch_bounds__(256) void prep_w(const float* __restrict__ cw,
                                              short* __restrict__ Bp) {
  int i = threadIdx.x + blockIdx.x * 256;
  if (i >= 576) return;
  int g = i >> 6, l = i & 63;
  int co = l & 15, kw = l >> 4;
  int kd = g / 3, kh = g % 3;
  short8 o;
#pragma unroll
  for (int j = 0; j < 8; ++j) {
    float v = (kw < 3) ? cw[(co * 8 + j) * 27 + kd * 9 + kh * 3 + kw] : 0.0f;
    o[j] = (short)f2bf_rn(v);
  }
  *(short8*)(Bp + (size_t)i * 8) = o;
}

__global__ __launch_bounds__(256, 4) void conv_mfma(const float* __restrict__ x,
                                                    const short* __restrict__ Bp,
                                                    float* __restrict__ partial) {
  __shared__ __align__(16) char lds[6 * 3072];  // 6-slab ring; slab=[r6][w32][ci8] bf16
  __shared__ float red[4];

  const int bid = blockIdx.x;                    // 1024 blocks
  const int swz = (bid & 7) * 128 + (bid >> 3);  // XCD-chunk, bijective
  const int b = swz >> 3, q = swz & 7;           // q: oh rows 4q..4q+3 (q=7: 2 rows)
  const int t = threadIdx.x, lane = t & 63, wv = t >> 6;
  const int nrows = (q == 7) ? 4 : 6;            // staged rows per plane
  const int row0 = 4 * q;
  const int nsite = 2 * nrows * 16;              // 192 / 128
  const float* xb = x + (size_t)b * 262144;

  // ---- staging decode: site = (plane-of-pair, local row, w-group of 2) ----
  const bool sact = t < nsite;
  const int ss = sact ? t : 0;
  const int spl = ss / (nrows * 16);
  const int rem = ss - spl * (nrows * 16);
  const int sr = rem >> 4, swg = rem & 15;
  const float* gsite = xb + (row0 + sr) * 32 + swg * 2;  // + plane*1024 + ci*32768

  auto issue = [&](int dpair, float2* v) {
    if (!sact) return;
    const float* gp = gsite + (dpair + spl) * 1024;
#pragma unroll
    for (int ci = 0; ci < 8; ++ci) v[ci] = *(const float2*)(gp + ci * 32768);
  };
  auto writeSlab = [&](int dpair, const float2* v) {
    if (!sact) return;
    const int d = dpair + spl;
    char* sb = lds + (d % 6) * 3072 + sr * 512;
#pragma unroll
    for (int wi = 0; wi < 2; ++wi) {
      const int w = swg * 2 + wi;
      uint4 o;  // truncation bf16 pack [ci0..ci7] (verified R6/R7)
      o.x = __builtin_amdgcn_perm(__float_as_uint(((const float*)&v[1])[wi]),
                                  __float_as_uint(((const float*)&v[0])[wi]), 0x07060302u);
      o.y = __builtin_amdgcn_perm(__float_as_uint(((const float*)&v[3])[wi]),
                                  __float_as_uint(((const float*)&v[2])[wi]), 0x07060302u);
      o.z = __builtin_amdgcn_perm(__float_as_uint(((const float*)&v[5])[wi]),
                                  __float_as_uint(((const float*)&v[4])[wi]), 0x07060302u);
      o.w = __builtin_amdgcn_perm(__float_as_uint(((const float*)&v[7])[wi]),
                                  __float_as_uint(((const float*)&v[6])[wi]), 0x07060302u);
      *(uint4*)(sb + ((w * 16) ^ (((w >> 3) & 3) << 4))) = o;
    }
  };

  // ---- B fragments (9 (kd,kh) groups) ----
  short8 Bw[9];
#pragma unroll
  for (int g = 0; g < 9; ++g)
    Bw[g] = *(const short8*)(Bp + ((size_t)g * 64 + lane) * 8);

  // ---- per-lane A addressing (verified R3): w = m + kw(tg), chunk1 +16 ----
  const int m = lane & 15, tg = lane >> 4;
  const int w0 = m + tg;
  int w1 = m + 16 + tg; if (w1 > 31) w1 = 31;  // clamp hits only masked/pad lanes
  const int wb0 = (w0 * 16) ^ (((w0 >> 3) & 3) << 4);
  const int wb1 = (w1 * 16) ^ (((w1 >> 3) & 3) << 4);

  // ---- task mapping: wave -> (oh-pair op, chunk c) ----
  const bool docomp = (q < 7) || (wv < 2);
  const int op = (q < 7) ? (wv >> 1) : 0;
  const int c  = (q < 7) ? (wv & 1) : wv;
  const int wbase = (c ? wb1 : wb0) + (2 * op) * 512;  // local row lr = 2*op

  // ---- prologue: stage planes 0..3 ----
  {
    float2 va[8], vb[8];
    issue(0, va); issue(2, vb);
    writeSlab(0, va); writeSlab(2, vb);
  }
  __syncthreads();

  // ---- main loop over pd ----
  float sum = 0.0f;
  for (int pd = 0; pd < 15; ++pd) {
    const bool more = (pd < 14);
    float2 va[8];
    if (more) issue(2 * pd + 4, va);  // prefetch next plane pair

    if (docomp) {
      const char* sb0 = lds + ((2 * pd)     % 6) * 3072 + wbase;
      const char* sb1 = lds + ((2 * pd + 1) % 6) * 3072 + wbase;
      const char* sb2 = lds + ((2 * pd + 2) % 6) * 3072 + wbase;
      const char* sb3 = lds + ((2 * pd + 3) % 6) * 3072 + wbase;
      const char* sbp[4] = {sb0, sb1, sb2, sb3};
      f32x4 cc[2][2] = {};  // [od][s]
#pragma unroll
      for (int p = 0; p < 4; ++p) {
#pragma unroll
        for (int rr = 0; rr < 4; ++rr) {
          const short8 a = *(const short8*)(sbp[p] + rr * 512);
          if (p < 3 && rr < 3)
            cc[0][0] = __builtin_amdgcn_mfma_f32_16x16x32_bf16(a, Bw[p * 3 + rr], cc[0][0], 0, 0, 0);
          if (p < 3 && rr > 0)
            cc[0][1] = __builtin_amdgcn_mfma_f32_16x16x32_bf16(a, Bw[p * 3 + rr - 1], cc[0][1], 0, 0, 0);
          if (p > 0 && rr < 3)
            cc[1][0] = __builtin_amdgcn_mfma_f32_16x16x32_bf16(a, Bw[(p - 1) * 3 + rr], cc[1][0], 0, 0, 0);
          if (p > 0 && rr > 0)
            cc[1][1] = __builtin_amdgcn_mfma_f32_16x16x32_bf16(a, Bw[(p - 1) * 3 + rr - 1], cc[1][1], 0, 0, 0);
        }
      }
      // maxpool 2x2x2 fully in-lane (od, s in regs; ow pairs = C row pairs)
#pragma unroll
      for (int p2 = 0; p2 < 2; ++p2) {
        float v = fmaxf(fmaxf(fmaxf(cc[0][0][2 * p2], cc[0][0][2 * p2 + 1]),
                              fmaxf(cc[0][1][2 * p2], cc[0][1][2 * p2 + 1])),
                        fmaxf(fmaxf(cc[1][0][2 * p2], cc[1][0][2 * p2 + 1]),
                              fmaxf(cc[1][1][2 * p2], cc[1][1][2 * p2 + 1])));
        const bool inval = (c == 1) && (tg == 3) && (p2 == 1);  // pw 15 invalid
        sum += inval ? 0.0f : v;
      }
    }

    if (more) writeSlab(2 * pd + 4, va);  // vmcnt wait + pack + ring write
    __syncthreads();
  }

  // ---- block reduction ----
#pragma unroll
  for (int off = 32; off; off >>= 1) sum += __shfl_down(sum, off);
  if (lane == 0) red[wv] = sum;
  __syncthreads();
  if (t == 0) partial[b * 8 + q] = red[0] + red[1] + red[2] + red[3];
}

__global__ __launch_bounds__(128) void finalize(const float* __restrict__ partial,
                                                const float* __restrict__ cb,
                                                const float* __restrict__ bias,
                                                float* __restrict__ out) {
  const int b = threadIdx.x;  // 128 threads, 1 block
  float k = 0.0f;
#pragma unroll
  for (int c = 0; c < 16; ++c) k += cb[c] * 0.5f + bias[c];
  float s = 0.0f;
#pragma unroll
  for (int q = 0; q < 8; ++q) s += partial[b * 8 + q];
  out[b] = s * (1.0f / 6750.0f) + k;
}

extern "C" void kernel_launch(void* const* d_in, const int* in_sizes, int n_in,
                              void* d_out, int out_size, void* d_ws, size_t ws_size,
                              hipStream_t stream) {
  const float* x    = (const float*)d_in[0];
  const float* cw   = (const float*)d_in[1];
  const float* cb   = (const float*)d_in[2];
  const float* bias = (const float*)d_in[3];
  float* out = (float*)d_out;

  short* Bp      = (short*)d_ws;                   // 576*16 B = 9216 B
  float* partial = (float*)((char*)d_ws + 32768);  // 1024 floats

  prep_w<<<3, 256, 0, stream>>>(cw, Bp);
  conv_mfma<<<1024, 256, 0, stream>>>(x, Bp, partial);
  finalize<<<1, 128, 0, stream>>>(partial, cb, bias, out);
}